// Round 2
// baseline (123.386 us; speedup 1.0000x reference)
//
#include <hip/hip_runtime.h>
#include <stdint.h>

// ---------------------------------------------------------------------------
// WindowedAttn: x(2,2048,1024) f32 -> QKV proj -> windowed causal attn (W=256)
// -> out proj. bf16 MFMA pipeline, f32 in/out.
// Round 2: 8-phase 256^2 GEMM (T2+T3+T4+T5) for QKV; barrier-free direct-load
// attention with pre-transposed V.
// ---------------------------------------------------------------------------

typedef __attribute__((ext_vector_type(8))) short bf16x8;     // 8 bf16 (4 VGPR)
typedef __attribute__((ext_vector_type(4))) float f32x4;      // MFMA C/D
typedef __attribute__((ext_vector_type(4))) unsigned int u32x4;
typedef __attribute__((ext_vector_type(4))) unsigned short u16x4;

#define DEV static __device__ __forceinline__

DEV unsigned short f2bf(float f) {            // f32 -> bf16 RNE
  unsigned int u = __builtin_bit_cast(unsigned int, f);
  u += 0x7fffu + ((u >> 16) & 1u);
  return (unsigned short)(u >> 16);
}

DEV void gload_lds16(const void* g, void* l) { // 16B global -> LDS direct
  __builtin_amdgcn_global_load_lds((const __attribute__((address_space(1))) void*)g,
                                   (__attribute__((address_space(3))) void*)l,
                                   16, 0, 0);
}

// --------------------------- fp32 -> bf16 ----------------------------------
__global__ __launch_bounds__(256) void k_f32_to_bf16(const float* __restrict__ in,
                                                     unsigned short* __restrict__ out,
                                                     int n4) {
  int i = blockIdx.x * 256 + threadIdx.x;
  if (i >= n4) return;
  f32x4 v = ((const f32x4*)in)[i];
  u16x4 o;
  o[0] = f2bf(v[0]); o[1] = f2bf(v[1]); o[2] = f2bf(v[2]); o[3] = f2bf(v[3]);
  ((u16x4*)out)[i] = o;
}

// ------------------- transpose + convert: out[n][k] = in[k][n] -------------
__global__ __launch_bounds__(256) void k_transpose_w(const float* __restrict__ in,
                                                     unsigned short* __restrict__ out,
                                                     int K, int N) {
  __shared__ float t[32][33];
  const int tx = threadIdx.x, ty = threadIdx.y;
  const int n0 = blockIdx.x * 32, k0 = blockIdx.y * 32;
#pragma unroll
  for (int i = 0; i < 4; ++i)
    t[ty + i * 8][tx] = in[(size_t)(k0 + ty + i * 8) * N + n0 + tx];
  __syncthreads();
#pragma unroll
  for (int i = 0; i < 4; ++i)
    out[(size_t)(n0 + ty + i * 8) * K + k0 + tx] = f2bf(t[tx][ty + i * 8]);
}

// ---------------- V transpose: vT[b*1024+hd][s] = qkv[b,s,2048+hd] ---------
__global__ __launch_bounds__(256) void k_transpose_v(const unsigned short* __restrict__ qkv,
                                                     unsigned short* __restrict__ vT) {
  __shared__ unsigned short t[64][80];      // 160B rows: 16B-aligned b128 reads
  const int tid = threadIdx.x;
  const int hd0 = blockIdx.x * 64;
  const int s0  = blockIdx.y * 64;
  const int b   = blockIdx.z;
  const unsigned short* src = qkv + (size_t)b * 2048 * 3072 + 2048;
#pragma unroll
  for (int rep = 0; rep < 2; ++rep) {
    int idx = rep * 256 + tid;              // 0..511
    int rs = idx >> 3;                      // s row 0..63
    int sl = idx & 7;                       // hd slot
    u32x4 v = *(const u32x4*)(src + (size_t)(s0 + rs) * 3072 + hd0 + sl * 8);
#pragma unroll
    for (int j = 0; j < 8; ++j)
      t[sl * 8 + j][rs] = (unsigned short)(v[j >> 1] >> ((j & 1) * 16));
  }
  __syncthreads();
  unsigned short* dst = vT + (size_t)b * 1024 * 2048;
#pragma unroll
  for (int rep = 0; rep < 2; ++rep) {
    int idx = rep * 256 + tid;
    int hd = idx >> 3;                      // 0..63
    int sl = idx & 7;                       // s slot
    *(u32x4*)(dst + (size_t)(hd0 + hd) * 2048 + s0 + sl * 8) = *(const u32x4*)&t[hd][sl * 8];
  }
}

// ---------------- 8-phase 256^2 GEMM (bf16 out), K multiple of 64, NT>=3 ----
// C[M][N] = A[M][K] @ Bt[N][K]^T + bias. 8 waves (2M x 4N), per-wave 128x64.
// LDS: per matrix a ring of 4 K-half slots (256 rows x 32 k, 16KB each).
// K-half stream h = 2*tile + khalf; slot = h & 3.
// Staging: gload_lds width-16, linear dest, XOR source pre-swizzle
// (k-slot ^= (row>>1)&3) so fragment ds_read_b128 is 2-way (free).
// Schedule per K-tile t (phases): ph0 Mh0xKh0 + stage A_o(t+1);
// ph1 Mh1xKh0 + stage B_o(t+1) + vmcnt(8); ph2 Mh0xKh1 + stage A_e(t+2);
// ph3 Mh1xKh1 + stage B_e(t+2) + vmcnt(8). vmcnt never drains to 0.
__global__ __launch_bounds__(512, 2) void k_gemm8(const unsigned short* __restrict__ A,
                                                  const unsigned short* __restrict__ Bt,
                                                  const float* __restrict__ bias,
                                                  unsigned short* __restrict__ C,
                                                  int M, int N, int K) {
  extern __shared__ unsigned short lds[];
  unsigned short* As = lds;                 // [4][256][32]
  unsigned short* Bs = lds + 32768;
  const int tid = threadIdx.x, lane = tid & 63, wid = tid >> 6;
  const int wr = wid >> 2, wc = wid & 3;    // 2M x 4N waves
  const int g = lane >> 4, li = lane & 15;
  const int m0 = blockIdx.y * 256, n0 = blockIdx.x * 256;
  const int NT = K >> 6;                    // K-tiles of 64 (assume NT >= 3)
  const int kp = g ^ ((li >> 1) & 3);       // physical k-slot for frag reads
  const int skl = (lane & 3) ^ ((lane >> 3) & 3);  // logical k-slot for staging

  f32x4 acc[8][4] = {};

  // stage one K-half (16KB) of A or B into ring slot h&3
  auto stageA = [&](int h) {
    int slot = h & 3;
#pragma unroll
    for (int j = 0; j < 2; ++j) {
      int chunk = wid * 2 + j;                         // 0..15
      int row = chunk * 16 + (lane >> 2);              // 0..255
      const unsigned short* src = A + (size_t)(m0 + row) * K + h * 32 + skl * 8;
      gload_lds16(src, &As[slot * 8192 + chunk * 512]);
    }
  };
  auto stageB = [&](int h) {
    int slot = h & 3;
#pragma unroll
    for (int j = 0; j < 2; ++j) {
      int chunk = wid * 2 + j;
      int row = chunk * 16 + (lane >> 2);
      const unsigned short* src = Bt + (size_t)(n0 + row) * K + h * 32 + skl * 8;
      gload_lds16(src, &Bs[slot * 8192 + chunk * 512]);
    }
  };
  auto fragA = [&](int slot, int mi) -> bf16x8 {
    return *(const bf16x8*)&As[slot * 8192 + (wr * 128 + mi * 16 + li) * 32 + kp * 8];
  };
  auto fragB = [&](int slot, int nj) -> bf16x8 {
    return *(const bf16x8*)&Bs[slot * 8192 + (wc * 64 + nj * 16 + li) * 32 + kp * 8];
  };

#define MFMA16(MB, A0, A1, A2, A3)                                                   \
  __builtin_amdgcn_s_setprio(1);                                                     \
  _Pragma("unroll")                                                                  \
  for (int jj = 0; jj < 4; ++jj) {                                                   \
    acc[(MB) + 0][jj] = __builtin_amdgcn_mfma_f32_16x16x32_bf16(A0, bb[jj], acc[(MB) + 0][jj], 0, 0, 0); \
    acc[(MB) + 1][jj] = __builtin_amdgcn_mfma_f32_16x16x32_bf16(A1, bb[jj], acc[(MB) + 1][jj], 0, 0, 0); \
    acc[(MB) + 2][jj] = __builtin_amdgcn_mfma_f32_16x16x32_bf16(A2, bb[jj], acc[(MB) + 2][jj], 0, 0, 0); \
    acc[(MB) + 3][jj] = __builtin_amdgcn_mfma_f32_16x16x32_bf16(A3, bb[jj], acc[(MB) + 3][jj], 0, 0, 0); \
  }                                                                                  \
  __builtin_amdgcn_s_setprio(0);

#define WAIT_LGKM()                                        \
  asm volatile("s_waitcnt lgkmcnt(0)" ::: "memory");       \
  __builtin_amdgcn_sched_barrier(0);

  // prologue: stream order Ae0,Be0,Ao0,Bo0,Ae1,Be1 (12 loads); oldest 4 done
  stageA(0); stageB(0); stageA(1); stageB(1); stageA(2); stageB(2);
  asm volatile("s_waitcnt vmcnt(8)" ::: "memory");
  __builtin_amdgcn_s_barrier();

  for (int t = 0; t < NT; ++t) {
    const int se = (2 * t) & 3, so = (2 * t + 1) & 3;
    bf16x8 bb[4];
    // ---- phase 0: Mhalf0 x khalf0 ----
    {
      bf16x8 a0 = fragA(se, 0), a1 = fragA(se, 1), a2 = fragA(se, 2), a3 = fragA(se, 3);
      bb[0] = fragB(se, 0); bb[1] = fragB(se, 1); bb[2] = fragB(se, 2); bb[3] = fragB(se, 3);
      if (t + 1 < NT) stageA(2 * t + 3);
      __builtin_amdgcn_s_barrier();
      WAIT_LGKM();
      MFMA16(0, a0, a1, a2, a3);
      __builtin_amdgcn_s_barrier();
    }
    // ---- phase 1: Mhalf1 x khalf0 (B reused) ----
    {
      bf16x8 a0 = fragA(se, 4), a1 = fragA(se, 5), a2 = fragA(se, 6), a3 = fragA(se, 7);
      if (t + 1 < NT) stageB(2 * t + 3);
      __builtin_amdgcn_s_barrier();
      WAIT_LGKM();
      MFMA16(4, a0, a1, a2, a3);
      asm volatile("s_waitcnt vmcnt(8)" ::: "memory");
      __builtin_amdgcn_s_barrier();
    }
    // ---- phase 2: Mhalf0 x khalf1 ----
    {
      bf16x8 a0 = fragA(so, 0), a1 = fragA(so, 1), a2 = fragA(so, 2), a3 = fragA(so, 3);
      bb[0] = fragB(so, 0); bb[1] = fragB(so, 1); bb[2] = fragB(so, 2); bb[3] = fragB(so, 3);
      if (t + 2 < NT) stageA(2 * t + 4);
      __builtin_amdgcn_s_barrier();
      WAIT_LGKM();
      MFMA16(0, a0, a1, a2, a3);
      __builtin_amdgcn_s_barrier();
    }
    // ---- phase 3: Mhalf1 x khalf1 ----
    {
      bf16x8 a0 = fragA(so, 4), a1 = fragA(so, 5), a2 = fragA(so, 6), a3 = fragA(so, 7);
      if (t + 2 < NT) stageB(2 * t + 4);
      __builtin_amdgcn_s_barrier();
      WAIT_LGKM();
      MFMA16(4, a0, a1, a2, a3);
      asm volatile("s_waitcnt vmcnt(8)" ::: "memory");
      __builtin_amdgcn_s_barrier();
    }
  }

  // epilogue: C/D layout col = li, row = g*4 + reg
#pragma unroll
  for (int nj = 0; nj < 4; ++nj) {
    const int col = n0 + wc * 64 + nj * 16 + li;
    const float bv = bias[col];
#pragma unroll
    for (int mi = 0; mi < 8; ++mi) {
#pragma unroll
      for (int reg = 0; reg < 4; ++reg) {
        const int row = m0 + wr * 128 + mi * 16 + g * 4 + reg;
        C[(size_t)row * N + col] = f2bf(acc[mi][nj][reg] + bv);
      }
    }
  }
#undef MFMA16
#undef WAIT_LGKM
}

// --------------------------- bf16 GEMM (128^2, f32 out) --------------------
// Used for the out-projection (N=1024 -> 256 blocks fill all CUs).
template <bool F32OUT>
__global__ __launch_bounds__(256) void k_gemm(const unsigned short* __restrict__ A,
                                              const unsigned short* __restrict__ Bt,
                                              const float* __restrict__ bias,
                                              void* __restrict__ Cout,
                                              int M, int N, int K) {
  __shared__ unsigned short As[128 * 32];
  __shared__ unsigned short Bs[128 * 32];
  const int tid = threadIdx.x;
  const int lane = tid & 63, wid = tid >> 6;
  const int wr = wid >> 1, wc = wid & 1;
  const int g = lane >> 4, li = lane & 15;
  const int m0 = blockIdx.y * 128, n0 = blockIdx.x * 128;

  f32x4 acc[4][4] = {};
  const int nkt = K >> 5;
  const int srow_in_chunk = lane >> 2;
  const int skp = lane & 3;

  auto stage = [&](int kt) {
#pragma unroll
    for (int half = 0; half < 2; ++half) {
      int chunk = wid * 2 + half;
      int row_p = chunk * 16 + srow_in_chunk;
      int row_l = row_p ^ ((row_p >> 3) & 1);
      int ks_l  = skp ^ ((row_p >> 1) & 3);
      const unsigned short* ga = A  + (size_t)(m0 + row_l) * K + kt * 32 + ks_l * 8;
      const unsigned short* gb = Bt + (size_t)(n0 + row_l) * K + kt * 32 + ks_l * 8;
      gload_lds16(ga, &As[chunk * 512]);
      gload_lds16(gb, &Bs[chunk * 512]);
    }
  };

  stage(0);
  for (int kt = 0; kt < nkt; ++kt) {
    __syncthreads();
    bf16x8 af[4], bfr[4];
#pragma unroll
    for (int mi = 0; mi < 4; ++mi) {
      int r = wr * 64 + mi * 16 + li;
      int rr = r ^ ((r >> 3) & 1);
      int ks = g ^ ((r >> 1) & 3);
      af[mi] = *(const bf16x8*)&As[rr * 32 + (ks << 3)];
    }
#pragma unroll
    for (int ni = 0; ni < 4; ++ni) {
      int r = wc * 64 + ni * 16 + li;
      int rr = r ^ ((r >> 3) & 1);
      int ks = g ^ ((r >> 1) & 3);
      bfr[ni] = *(const bf16x8*)&Bs[rr * 32 + (ks << 3)];
    }
#pragma unroll
    for (int mi = 0; mi < 4; ++mi)
#pragma unroll
      for (int ni = 0; ni < 4; ++ni)
        acc[mi][ni] = __builtin_amdgcn_mfma_f32_16x16x32_bf16(af[mi], bfr[ni],
                                                              acc[mi][ni], 0, 0, 0);
    if (kt + 1 < nkt) {
      __syncthreads();
      stage(kt + 1);
    }
  }

  float bv[4];
#pragma unroll
  for (int ni = 0; ni < 4; ++ni) bv[ni] = bias[n0 + wc * 64 + ni * 16 + li];
#pragma unroll
  for (int mi = 0; mi < 4; ++mi) {
#pragma unroll
    for (int ni = 0; ni < 4; ++ni) {
      const int col = n0 + wc * 64 + ni * 16 + li;
#pragma unroll
      for (int reg = 0; reg < 4; ++reg) {
        const int row = m0 + wr * 64 + mi * 16 + g * 4 + reg;
        float v = acc[mi][ni][reg] + bv[ni];
        if (F32OUT) ((float*)Cout)[(size_t)row * N + col] = v;
        else ((unsigned short*)Cout)[(size_t)row * N + col] = f2bf(v);
      }
    }
  }
}

// ------------------ windowed flash attention (barrier-free) ----------------
// qkv: (4096, 3072) bf16 = [Q|K|V]; vT: (2048 rows bh*64+d, 2048 keys) bf16.
// Block = one (b,h,q-tile of 64), 4 independent waves x 16 q-rows.
// K/Q/V fragments load directly from global (L1/L2-resident tiles); only the
// P round-trip uses (wave-private) LDS -> no __syncthreads anywhere.
__global__ __launch_bounds__(256) void k_attn2(const unsigned short* __restrict__ qkv,
                                               const unsigned short* __restrict__ vT,
                                               unsigned short* __restrict__ attn) {
  __shared__ unsigned short Ps[64 * 88];
  const int tid = threadIdx.x, lane = tid & 63, wid = tid >> 6;
  const int g = lane >> 4, li = lane & 15;
  const int bh = blockIdx.y, b = bh >> 4, h = bh & 15;
  const int q0 = blockIdx.x * 64;
  const size_t rs = 3072;
  const unsigned short* qb = qkv + (size_t)b * 2048 * rs + h * 64;
  const unsigned short* kb = qb + 1024;
  const unsigned short* vb = vT + (size_t)bh * 64 * 2048;

  const int qrow = wid * 16 + li;
  const bf16x8 qf0 = *(const bf16x8*)(qb + (size_t)(q0 + qrow) * rs + (g << 3));
  const bf16x8 qf1 = *(const bf16x8*)(qb + (size_t)(q0 + qrow) * rs + 32 + (g << 3));

  f32x4 o[4] = {};
  float m_run[4] = {-3e30f, -3e30f, -3e30f, -3e30f};
  float l_part[4] = {0.f, 0.f, 0.f, 0.f};

  for (int t = 0; t < 5; ++t) {
    const int j0 = q0 - 256 + t * 64;
    if (j0 < 0) continue;                  // uniform across block

    // ---- S = (Q K^T) * scale, masked ----
    f32x4 s[4];
#pragma unroll
    for (int ni = 0; ni < 4; ++ni) {
      const unsigned short* kr = kb + (size_t)(j0 + ni * 16 + li) * rs;
      bf16x8 kf0 = *(const bf16x8*)(kr + (g << 3));
      bf16x8 kf1 = *(const bf16x8*)(kr + 32 + (g << 3));
      f32x4 z = {};
      z = __builtin_amdgcn_mfma_f32_16x16x32_bf16(qf0, kf0, z, 0, 0, 0);
      z = __builtin_amdgcn_mfma_f32_16x16x32_bf16(qf1, kf1, z, 0, 0, 0);
      s[ni] = z;
    }
    const int rt = wid * 16 + g * 4;       // + reg = q row in tile
#pragma unroll
    for (int ni = 0; ni < 4; ++ni) {
      int ct = ni * 16 + li;               // key col in tile
#pragma unroll
      for (int reg = 0; reg < 4; ++reg) {
        float sv = s[ni][reg] * 0.125f;
        if (t == 4 && ct > rt + reg) sv = -3e30f;   // causal
        if (t == 0 && ct < rt + reg) sv = -3e30f;   // window lower bound
        s[ni][reg] = sv;
      }
    }
    // ---- online softmax ----
    float alpha[4];
#pragma unroll
    for (int reg = 0; reg < 4; ++reg) {
      float mx = fmaxf(fmaxf(s[0][reg], s[1][reg]), fmaxf(s[2][reg], s[3][reg]));
      mx = fmaxf(mx, __shfl_xor(mx, 1, 64));
      mx = fmaxf(mx, __shfl_xor(mx, 2, 64));
      mx = fmaxf(mx, __shfl_xor(mx, 4, 64));
      mx = fmaxf(mx, __shfl_xor(mx, 8, 64));
      float mnew = fmaxf(m_run[reg], mx);
      alpha[reg] = __expf(m_run[reg] - mnew);
      m_run[reg] = mnew;
    }
#pragma unroll
    for (int reg = 0; reg < 4; ++reg) {
      float ps = 0.f;
#pragma unroll
      for (int ni = 0; ni < 4; ++ni) {
        float p = __expf(s[ni][reg] - m_run[reg]);
        ps += p;
        Ps[(wid * 16 + g * 4 + reg) * 88 + ni * 16 + li] = f2bf(p);
      }
      l_part[reg] = l_part[reg] * alpha[reg] + ps;
#pragma unroll
      for (int ni = 0; ni < 4; ++ni) o[ni][reg] *= alpha[reg];
    }
    // wave-private P round-trip: explicit wait + sched fence (rule #18)
    asm volatile("s_waitcnt lgkmcnt(0)" ::: "memory");
    __builtin_amdgcn_sched_barrier(0);
    const bf16x8 pf0 = *(const bf16x8*)&Ps[(wid * 16 + li) * 88 + (g << 3)];
    const bf16x8 pf1 = *(const bf16x8*)&Ps[(wid * 16 + li) * 88 + 32 + (g << 3)];
    // ---- PV: B-frags straight from vT ----
#pragma unroll
    for (int ni = 0; ni < 4; ++ni) {
      const unsigned short* vr = vb + (size_t)(ni * 16 + li) * 2048 + j0;
      bf16x8 vf0 = *(const bf16x8*)(vr + (g << 3));
      bf16x8 vf1 = *(const bf16x8*)(vr + 32 + (g << 3));
      o[ni] = __builtin_amdgcn_mfma_f32_16x16x32_bf16(pf0, vf0, o[ni], 0, 0, 0);
      o[ni] = __builtin_amdgcn_mfma_f32_16x16x32_bf16(pf1, vf1, o[ni], 0, 0, 0);
    }
  }

  // ---- normalize + store ((B*S, 1024) bf16) ----
  float inv[4];
#pragma unroll
  for (int reg = 0; reg < 4; ++reg) {
    float L = l_part[reg];
    L += __shfl_xor(L, 1, 64);
    L += __shfl_xor(L, 2, 64);
    L += __shfl_xor(L, 4, 64);
    L += __shfl_xor(L, 8, 64);
    inv[reg] = 1.f / L;
  }
#pragma unroll
  for (int ni = 0; ni < 4; ++ni) {
#pragma unroll
    for (int reg = 0; reg < 4; ++reg) {
      size_t row = (size_t)b * 2048 + q0 + wid * 16 + g * 4 + reg;
      attn[row * 1024 + h * 64 + ni * 16 + li] = f2bf(o[ni][reg] * inv[reg]);
    }
  }
}

// ---------------------------------------------------------------------------
extern "C" void kernel_launch(void* const* d_in, const int* in_sizes, int n_in,
                              void* d_out, int out_size, void* d_ws, size_t ws_size,
                              hipStream_t stream) {
  const float* x    = (const float*)d_in[0];   // (4096, 1024)
  const float* Wqkv = (const float*)d_in[1];   // (1024, 3072)
  const float* bqkv = (const float*)d_in[2];   // (3072)
  const float* Wout = (const float*)d_in[3];   // (1024, 1024)
  const float* bout = (const float*)d_in[4];   // (1024)
  float* out = (float*)d_out;                  // (4096, 1024)

  uint8_t* ws = (uint8_t*)d_ws;
  unsigned short* xb    = (unsigned short*)(ws);              //  8.0 MB x bf16
  unsigned short* wqT   = (unsigned short*)(ws +  8388608);   //  6.0 MB Wqkv^T
  unsigned short* woT   = (unsigned short*)(ws + 14680064);   //  2.0 MB Wout^T
  unsigned short* qkvb  = (unsigned short*)(ws + 16777216);   // 24.0 MB qkv
  unsigned short* attnb = (unsigned short*)(ws + 41943040);   //  8.0 MB attn out
  unsigned short* vTb   = (unsigned short*)(ws + 50331648);   //  8.0 MB V^T

  hipFuncSetAttribute((const void*)k_gemm8,
                      hipFuncAttributeMaxDynamicSharedMemorySize, 131072);

  k_f32_to_bf16<<<4096, 256, 0, stream>>>(x, xb, 1048576);
  k_transpose_w<<<dim3(3072 / 32, 1024 / 32), dim3(32, 8), 0, stream>>>(Wqkv, wqT, 1024, 3072);
  k_transpose_w<<<dim3(1024 / 32, 1024 / 32), dim3(32, 8), 0, stream>>>(Wout, woT, 1024, 1024);
  k_gemm8<<<dim3(3072 / 256, 4096 / 256), 512, 131072, stream>>>(xb, wqT, bqkv, qkvb,
                                                                 4096, 3072, 1024);
  k_transpose_v<<<dim3(16, 32, 2), 256, 0, stream>>>(qkvb, vTb);
  k_attn2<<<dim3(2048 / 64, 32), 256, 0, stream>>>(qkvb, vTb, attnb);
  k_gemm<true><<<dim3(1024 / 128, 4096 / 128), 256, 0, stream>>>(attnb, woT, bout, out,
                                                                 4096, 1024, 1024);
}

// Round 3
// 105.541 us; speedup vs baseline: 1.1691x; 1.1691x over previous
//
#include <hip/hip_runtime.h>
#include <stdint.h>

// ---------------------------------------------------------------------------
// WindowedAttn: x(2,2048,1024) f32 -> QKV proj -> windowed causal attn (W=256)
// -> out proj. bf16 MFMA pipeline, f32 in/out.
// Round 3: attn re-staged via global_load_lds + counted vmcnt double-buffer
// (V from pre-transposed vT, no scatter); out-proj 128x64 tiles (2-3 blk/CU).
// ---------------------------------------------------------------------------

typedef __attribute__((ext_vector_type(8))) short bf16x8;     // 8 bf16 (4 VGPR)
typedef __attribute__((ext_vector_type(4))) float f32x4;      // MFMA C/D
typedef __attribute__((ext_vector_type(4))) unsigned int u32x4;
typedef __attribute__((ext_vector_type(4))) unsigned short u16x4;

#define DEV static __device__ __forceinline__

DEV unsigned short f2bf(float f) {            // f32 -> bf16 RNE
  unsigned int u = __builtin_bit_cast(unsigned int, f);
  u += 0x7fffu + ((u >> 16) & 1u);
  return (unsigned short)(u >> 16);
}

DEV void gload_lds16(const void* g, void* l) { // 16B global -> LDS direct
  __builtin_amdgcn_global_load_lds((const __attribute__((address_space(1))) void*)g,
                                   (__attribute__((address_space(3))) void*)l,
                                   16, 0, 0);
}

// --------------------------- fp32 -> bf16 ----------------------------------
__global__ __launch_bounds__(256) void k_f32_to_bf16(const float* __restrict__ in,
                                                     unsigned short* __restrict__ out,
                                                     int n4) {
  int i = blockIdx.x * 256 + threadIdx.x;
  if (i >= n4) return;
  f32x4 v = ((const f32x4*)in)[i];
  u16x4 o;
  o[0] = f2bf(v[0]); o[1] = f2bf(v[1]); o[2] = f2bf(v[2]); o[3] = f2bf(v[3]);
  ((u16x4*)out)[i] = o;
}

// ------------------- transpose + convert: out[n][k] = in[k][n] -------------
__global__ __launch_bounds__(256) void k_transpose_w(const float* __restrict__ in,
                                                     unsigned short* __restrict__ out,
                                                     int K, int N) {
  __shared__ float t[32][33];
  const int tx = threadIdx.x, ty = threadIdx.y;
  const int n0 = blockIdx.x * 32, k0 = blockIdx.y * 32;
#pragma unroll
  for (int i = 0; i < 4; ++i)
    t[ty + i * 8][tx] = in[(size_t)(k0 + ty + i * 8) * N + n0 + tx];
  __syncthreads();
#pragma unroll
  for (int i = 0; i < 4; ++i)
    out[(size_t)(n0 + ty + i * 8) * K + k0 + tx] = f2bf(t[tx][ty + i * 8]);
}

// ---------------- V transpose: vT[b*1024+hd][s] = qkv[b,s,2048+hd] ---------
__global__ __launch_bounds__(256) void k_transpose_v(const unsigned short* __restrict__ qkv,
                                                     unsigned short* __restrict__ vT) {
  __shared__ unsigned short t[64][80];
  const int tid = threadIdx.x;
  const int hd0 = blockIdx.x * 64;
  const int s0  = blockIdx.y * 64;
  const int b   = blockIdx.z;
  const unsigned short* src = qkv + (size_t)b * 2048 * 3072 + 2048;
#pragma unroll
  for (int rep = 0; rep < 2; ++rep) {
    int idx = rep * 256 + tid;
    int rs = idx >> 3;
    int sl = idx & 7;
    u32x4 v = *(const u32x4*)(src + (size_t)(s0 + rs) * 3072 + hd0 + sl * 8);
#pragma unroll
    for (int j = 0; j < 8; ++j)
      t[sl * 8 + j][rs] = (unsigned short)(v[j >> 1] >> ((j & 1) * 16));
  }
  __syncthreads();
  unsigned short* dst = vT + (size_t)b * 1024 * 2048;
#pragma unroll
  for (int rep = 0; rep < 2; ++rep) {
    int idx = rep * 256 + tid;
    int hd = idx >> 3;
    int sl = idx & 7;
    *(u32x4*)(dst + (size_t)(hd0 + hd) * 2048 + s0 + sl * 8) = *(const u32x4*)&t[hd][sl * 8];
  }
}

// ---------------- 8-phase 256^2 GEMM (bf16 out), K multiple of 64, NT>=3 ----
__global__ __launch_bounds__(512, 2) void k_gemm8(const unsigned short* __restrict__ A,
                                                  const unsigned short* __restrict__ Bt,
                                                  const float* __restrict__ bias,
                                                  unsigned short* __restrict__ C,
                                                  int M, int N, int K) {
  extern __shared__ unsigned short lds[];
  unsigned short* As = lds;                 // [4][256][32]
  unsigned short* Bs = lds + 32768;
  const int tid = threadIdx.x, lane = tid & 63, wid = tid >> 6;
  const int wr = wid >> 2, wc = wid & 3;    // 2M x 4N waves
  const int g = lane >> 4, li = lane & 15;
  const int m0 = blockIdx.y * 256, n0 = blockIdx.x * 256;
  const int NT = K >> 6;
  const int kp = g ^ ((li >> 1) & 3);
  const int skl = (lane & 3) ^ ((lane >> 3) & 3);

  f32x4 acc[8][4] = {};

  auto stageA = [&](int h) {
    int slot = h & 3;
#pragma unroll
    for (int j = 0; j < 2; ++j) {
      int chunk = wid * 2 + j;
      int row = chunk * 16 + (lane >> 2);
      const unsigned short* src = A + (size_t)(m0 + row) * K + h * 32 + skl * 8;
      gload_lds16(src, &As[slot * 8192 + chunk * 512]);
    }
  };
  auto stageB = [&](int h) {
    int slot = h & 3;
#pragma unroll
    for (int j = 0; j < 2; ++j) {
      int chunk = wid * 2 + j;
      int row = chunk * 16 + (lane >> 2);
      const unsigned short* src = Bt + (size_t)(n0 + row) * K + h * 32 + skl * 8;
      gload_lds16(src, &Bs[slot * 8192 + chunk * 512]);
    }
  };
  auto fragA = [&](int slot, int mi) -> bf16x8 {
    return *(const bf16x8*)&As[slot * 8192 + (wr * 128 + mi * 16 + li) * 32 + kp * 8];
  };
  auto fragB = [&](int slot, int nj) -> bf16x8 {
    return *(const bf16x8*)&Bs[slot * 8192 + (wc * 64 + nj * 16 + li) * 32 + kp * 8];
  };

#define MFMA16(MB, A0, A1, A2, A3)                                                   \
  __builtin_amdgcn_s_setprio(1);                                                     \
  _Pragma("unroll")                                                                  \
  for (int jj = 0; jj < 4; ++jj) {                                                   \
    acc[(MB) + 0][jj] = __builtin_amdgcn_mfma_f32_16x16x32_bf16(A0, bb[jj], acc[(MB) + 0][jj], 0, 0, 0); \
    acc[(MB) + 1][jj] = __builtin_amdgcn_mfma_f32_16x16x32_bf16(A1, bb[jj], acc[(MB) + 1][jj], 0, 0, 0); \
    acc[(MB) + 2][jj] = __builtin_amdgcn_mfma_f32_16x16x32_bf16(A2, bb[jj], acc[(MB) + 2][jj], 0, 0, 0); \
    acc[(MB) + 3][jj] = __builtin_amdgcn_mfma_f32_16x16x32_bf16(A3, bb[jj], acc[(MB) + 3][jj], 0, 0, 0); \
  }                                                                                  \
  __builtin_amdgcn_s_setprio(0);

#define WAIT_LGKM()                                        \
  asm volatile("s_waitcnt lgkmcnt(0)" ::: "memory");       \
  __builtin_amdgcn_sched_barrier(0);

  stageA(0); stageB(0); stageA(1); stageB(1); stageA(2); stageB(2);
  asm volatile("s_waitcnt vmcnt(8)" ::: "memory");
  __builtin_amdgcn_s_barrier();

  for (int t = 0; t < NT; ++t) {
    const int se = (2 * t) & 3, so = (2 * t + 1) & 3;
    bf16x8 bb[4];
    {
      bf16x8 a0 = fragA(se, 0), a1 = fragA(se, 1), a2 = fragA(se, 2), a3 = fragA(se, 3);
      bb[0] = fragB(se, 0); bb[1] = fragB(se, 1); bb[2] = fragB(se, 2); bb[3] = fragB(se, 3);
      if (t + 1 < NT) stageA(2 * t + 3);
      __builtin_amdgcn_s_barrier();
      WAIT_LGKM();
      MFMA16(0, a0, a1, a2, a3);
      __builtin_amdgcn_s_barrier();
    }
    {
      bf16x8 a0 = fragA(se, 4), a1 = fragA(se, 5), a2 = fragA(se, 6), a3 = fragA(se, 7);
      if (t + 1 < NT) stageB(2 * t + 3);
      __builtin_amdgcn_s_barrier();
      WAIT_LGKM();
      MFMA16(4, a0, a1, a2, a3);
      asm volatile("s_waitcnt vmcnt(8)" ::: "memory");
      __builtin_amdgcn_s_barrier();
    }
    {
      bf16x8 a0 = fragA(so, 0), a1 = fragA(so, 1), a2 = fragA(so, 2), a3 = fragA(so, 3);
      bb[0] = fragB(so, 0); bb[1] = fragB(so, 1); bb[2] = fragB(so, 2); bb[3] = fragB(so, 3);
      if (t + 2 < NT) stageA(2 * t + 4);
      __builtin_amdgcn_s_barrier();
      WAIT_LGKM();
      MFMA16(0, a0, a1, a2, a3);
      __builtin_amdgcn_s_barrier();
    }
    {
      bf16x8 a0 = fragA(so, 4), a1 = fragA(so, 5), a2 = fragA(so, 6), a3 = fragA(so, 7);
      if (t + 2 < NT) stageB(2 * t + 4);
      __builtin_amdgcn_s_barrier();
      WAIT_LGKM();
      MFMA16(4, a0, a1, a2, a3);
      asm volatile("s_waitcnt vmcnt(8)" ::: "memory");
      __builtin_amdgcn_s_barrier();
    }
  }

#pragma unroll
  for (int nj = 0; nj < 4; ++nj) {
    const int col = n0 + wc * 64 + nj * 16 + li;
    const float bv = bias[col];
#pragma unroll
    for (int mi = 0; mi < 8; ++mi) {
#pragma unroll
      for (int reg = 0; reg < 4; ++reg) {
        const int row = m0 + wr * 128 + mi * 16 + g * 4 + reg;
        C[(size_t)row * N + col] = f2bf(acc[mi][nj][reg] + bv);
      }
    }
  }
#undef MFMA16
#undef WAIT_LGKM
}

// ------------------ bf16 GEMM, 128 x BN tile, 4 waves ----------------------
// BN=128: waves 2x2 of 64x64 (grid-heavy cases). BN=64: waves 2x2 of 64x32 ->
// 512 blocks for M=4096,N=1024 -> 2-3 blocks/CU (the m97 structure needs
// co-resident blocks to hide the barrier drain).
template <int BN, bool F32OUT>
__global__ __launch_bounds__(256) void k_gemm(const unsigned short* __restrict__ A,
                                              const unsigned short* __restrict__ Bt,
                                              const float* __restrict__ bias,
                                              void* __restrict__ Cout,
                                              int M, int N, int K) {
  constexpr int NI = BN / 32;               // B-frags per wave
  __shared__ unsigned short As[128 * 32];
  __shared__ unsigned short Bs[BN * 32];
  const int tid = threadIdx.x;
  const int lane = tid & 63, wid = tid >> 6;
  const int wr = wid >> 1, wc = wid & 1;
  const int g = lane >> 4, li = lane & 15;
  const int m0 = blockIdx.y * 128, n0 = blockIdx.x * BN;
  const int nkt = K >> 5;
  const int kp = g ^ ((li >> 1) & 3);
  const int skl = (lane & 3) ^ ((lane >> 3) & 3);
  constexpr int NCH = 8 + BN / 16;          // 16-row chunks (A then B)

  f32x4 acc[4][NI] = {};

  auto stage = [&](int kt) {
#pragma unroll
    for (int c = wid; c < NCH; c += 4) {
      int rin = lane >> 2;
      if (c < 8) {
        int row = c * 16 + rin;
        gload_lds16(A + (size_t)(m0 + row) * K + kt * 32 + skl * 8, &As[c * 512]);
      } else {
        int row = (c - 8) * 16 + rin;
        gload_lds16(Bt + (size_t)(n0 + row) * K + kt * 32 + skl * 8, &Bs[(c - 8) * 512]);
      }
    }
  };

  stage(0);
  for (int kt = 0; kt < nkt; ++kt) {
    __syncthreads();
    bf16x8 af[4], bfr[NI];
#pragma unroll
    for (int mi = 0; mi < 4; ++mi)
      af[mi] = *(const bf16x8*)&As[(wr * 64 + mi * 16 + li) * 32 + kp * 8];
#pragma unroll
    for (int ni = 0; ni < NI; ++ni)
      bfr[ni] = *(const bf16x8*)&Bs[(wc * (BN / 2) + ni * 16 + li) * 32 + kp * 8];
#pragma unroll
    for (int mi = 0; mi < 4; ++mi)
#pragma unroll
      for (int ni = 0; ni < NI; ++ni)
        acc[mi][ni] = __builtin_amdgcn_mfma_f32_16x16x32_bf16(af[mi], bfr[ni],
                                                              acc[mi][ni], 0, 0, 0);
    if (kt + 1 < nkt) {
      __syncthreads();
      stage(kt + 1);
    }
  }

  float bv[NI];
#pragma unroll
  for (int ni = 0; ni < NI; ++ni) bv[ni] = bias[n0 + wc * (BN / 2) + ni * 16 + li];
#pragma unroll
  for (int mi = 0; mi < 4; ++mi) {
#pragma unroll
    for (int ni = 0; ni < NI; ++ni) {
      const int col = n0 + wc * (BN / 2) + ni * 16 + li;
#pragma unroll
      for (int reg = 0; reg < 4; ++reg) {
        const int row = m0 + wr * 64 + mi * 16 + g * 4 + reg;
        float v = acc[mi][ni][reg] + bv[ni];
        if (F32OUT) ((float*)Cout)[(size_t)row * N + col] = v;
        else ((unsigned short*)Cout)[(size_t)row * N + col] = f2bf(v);
      }
    }
  }
}

// ------------------ windowed flash attention (staged, dbuf) ----------------
// qkv: (4096,3072) bf16 = [Q|K|V]; vT: per (b,h) 64 d-rows x 2048 keys.
// Block = (b,h,q-tile 64), 4 waves x 16 q-rows. Per key-tile of 64:
// K (row-major) and V^T staged via global_load_lds (linear dest, XOR slot
// pre-swizzle both sides), double-buffered with counted vmcnt(4) -> next
// tile's loads stay in flight under compute (T3/T4). Raw s_barrier only.
__global__ __launch_bounds__(256) void k_attn3(const unsigned short* __restrict__ qkv,
                                               const unsigned short* __restrict__ vT,
                                               unsigned short* __restrict__ attn) {
  __shared__ unsigned short Ks[2][64 * 64];  // swizzled: elem(row, s) at row*64 + (s^(row&7))*8
  __shared__ unsigned short Vs[2][64 * 64];  // V^T rows = d, cols = key
  __shared__ unsigned short Ps[64 * 88];     // wave-private 16-row regions
  const int tid = threadIdx.x, lane = tid & 63, wid = tid >> 6;
  const int g = lane >> 4, li = lane & 15;
  const int bh = blockIdx.y, b = bh >> 4, h = bh & 15;
  const int q0 = blockIdx.x * 64;
  const size_t rs = 3072;
  const unsigned short* qb = qkv + (size_t)b * 2048 * rs + h * 64;
  const unsigned short* kb = qb + 1024;
  const unsigned short* vb = vT + (size_t)bh * 64 * 2048;

  // Q frags direct from global (once per block)
  const int qrow = wid * 16 + li;
  const bf16x8 qf0 = *(const bf16x8*)(qb + (size_t)(q0 + qrow) * rs + (g << 3));
  const bf16x8 qf1 = *(const bf16x8*)(qb + (size_t)(q0 + qrow) * rs + 32 + (g << 3));

  const int tf = (blockIdx.x >= 4) ? 0 : (4 - (int)blockIdx.x);

  // stage key-tile t into buffer bufi: per wave 2 K-chunks + 2 V-chunks (4 gloads)
  auto stage = [&](int bufi, int t) {
    const int j0 = q0 - 256 + t * 64;
    const int sl = (lane & 7) ^ ((lane >> 3) & 7);  // logical k/key slot
#pragma unroll
    for (int j = 0; j < 2; ++j) {
      const int chunk = wid * 2 + j;                // 8 rows each
      const int row = chunk * 8 + (lane >> 3);
      gload_lds16(kb + (size_t)(j0 + row) * rs + sl * 8, &Ks[bufi][chunk * 512]);
      gload_lds16(vb + (size_t)row * 2048 + j0 + sl * 8, &Vs[bufi][chunk * 512]);
    }
  };

  f32x4 o[4] = {};
  float m_run[4] = {-3e30f, -3e30f, -3e30f, -3e30f};
  float l_part[4] = {0.f, 0.f, 0.f, 0.f};

  stage(0, tf);
  int cur = 0;
  for (int t = tf; t < 5; ++t) {
    if (t + 1 < 5) {
      stage(cur ^ 1, t + 1);
      asm volatile("s_waitcnt vmcnt(4)" ::: "memory");  // own tile-t loads landed
    } else {
      asm volatile("s_waitcnt vmcnt(0)" ::: "memory");
    }
    __builtin_amdgcn_sched_barrier(0);
    __builtin_amdgcn_s_barrier();            // all waves' tile-t data in LDS
    __builtin_amdgcn_sched_barrier(0);

    const unsigned short* Kc = Ks[cur];
    const unsigned short* Vc = Vs[cur];

    // ---- S = (Q K^T) * scale, masked ----
    f32x4 s[4];
#pragma unroll
    for (int ni = 0; ni < 4; ++ni) {
      const int kr = ni * 16 + li;
      const int sw = (kr & 7);
      bf16x8 kf0 = *(const bf16x8*)&Kc[kr * 64 + ((g ^ sw) << 3)];
      bf16x8 kf1 = *(const bf16x8*)&Kc[kr * 64 + (((4 + g) ^ sw) << 3)];
      f32x4 z = {};
      z = __builtin_amdgcn_mfma_f32_16x16x32_bf16(qf0, kf0, z, 0, 0, 0);
      z = __builtin_amdgcn_mfma_f32_16x16x32_bf16(qf1, kf1, z, 0, 0, 0);
      s[ni] = z;
    }
    const int rt = wid * 16 + g * 4;
#pragma unroll
    for (int ni = 0; ni < 4; ++ni) {
      int ct = ni * 16 + li;
#pragma unroll
      for (int reg = 0; reg < 4; ++reg) {
        float sv = s[ni][reg] * 0.125f;
        if (t == 4 && ct > rt + reg) sv = -3e30f;   // causal
        if (t == 0 && ct < rt + reg) sv = -3e30f;   // window lower bound
        s[ni][reg] = sv;
      }
    }
    // ---- online softmax ----
    float alpha[4];
#pragma unroll
    for (int reg = 0; reg < 4; ++reg) {
      float mx = fmaxf(fmaxf(s[0][reg], s[1][reg]), fmaxf(s[2][reg], s[3][reg]));
      mx = fmaxf(mx, __shfl_xor(mx, 1, 64));
      mx = fmaxf(mx, __shfl_xor(mx, 2, 64));
      mx = fmaxf(mx, __shfl_xor(mx, 4, 64));
      mx = fmaxf(mx, __shfl_xor(mx, 8, 64));
      float mnew = fmaxf(m_run[reg], mx);
      alpha[reg] = __expf(m_run[reg] - mnew);
      m_run[reg] = mnew;
    }
#pragma unroll
    for (int reg = 0; reg < 4; ++reg) {
      float ps = 0.f;
#pragma unroll
      for (int ni = 0; ni < 4; ++ni) {
        float p = __expf(s[ni][reg] - m_run[reg]);
        ps += p;
        Ps[(wid * 16 + g * 4 + reg) * 88 + ni * 16 + li] = f2bf(p);
      }
      l_part[reg] = l_part[reg] * alpha[reg] + ps;
#pragma unroll
      for (int ni = 0; ni < 4; ++ni) o[ni][reg] *= alpha[reg];
    }
    // wave-private P round-trip (rule #18: explicit wait + sched fence)
    asm volatile("s_waitcnt lgkmcnt(0)" ::: "memory");
    __builtin_amdgcn_sched_barrier(0);
    const bf16x8 pf0 = *(const bf16x8*)&Ps[(wid * 16 + li) * 88 + (g << 3)];
    const bf16x8 pf1 = *(const bf16x8*)&Ps[(wid * 16 + li) * 88 + 32 + (g << 3)];
    // ---- PV: B-frags from staged V^T ----
#pragma unroll
    for (int ni = 0; ni < 4; ++ni) {
      const int dr = ni * 16 + li;
      const int sw = (dr & 7);
      bf16x8 vf0 = *(const bf16x8*)&Vc[dr * 64 + ((g ^ sw) << 3)];
      bf16x8 vf1 = *(const bf16x8*)&Vc[dr * 64 + (((4 + g) ^ sw) << 3)];
      o[ni] = __builtin_amdgcn_mfma_f32_16x16x32_bf16(pf0, vf0, o[ni], 0, 0, 0);
      o[ni] = __builtin_amdgcn_mfma_f32_16x16x32_bf16(pf1, vf1, o[ni], 0, 0, 0);
    }
    __builtin_amdgcn_sched_barrier(0);
    __builtin_amdgcn_s_barrier();            // all reads of buf[cur] retired (WAR guard)
    cur ^= 1;
  }

  // ---- normalize + store ((B*S, 1024) bf16) ----
  float inv[4];
#pragma unroll
  for (int reg = 0; reg < 4; ++reg) {
    float L = l_part[reg];
    L += __shfl_xor(L, 1, 64);
    L += __shfl_xor(L, 2, 64);
    L += __shfl_xor(L, 4, 64);
    L += __shfl_xor(L, 8, 64);
    inv[reg] = 1.f / L;
  }
#pragma unroll
  for (int ni = 0; ni < 4; ++ni) {
#pragma unroll
    for (int reg = 0; reg < 4; ++reg) {
      size_t row = (size_t)b * 2048 + q0 + wid * 16 + g * 4 + reg;
      attn[row * 1024 + h * 64 + ni * 16 + li] = f2bf(o[ni][reg] * inv[reg]);
    }
  }
}

// ---------------------------------------------------------------------------
extern "C" void kernel_launch(void* const* d_in, const int* in_sizes, int n_in,
                              void* d_out, int out_size, void* d_ws, size_t ws_size,
                              hipStream_t stream) {
  const float* x    = (const float*)d_in[0];   // (4096, 1024)
  const float* Wqkv = (const float*)d_in[1];   // (1024, 3072)
  const float* bqkv = (const float*)d_in[2];   // (3072)
  const float* Wout = (const float*)d_in[3];   // (1024, 1024)
  const float* bout = (const float*)d_in[4];   // (1024)
  float* out = (float*)d_out;                  // (4096, 1024)

  uint8_t* ws = (uint8_t*)d_ws;
  unsigned short* xb    = (unsigned short*)(ws);              //  8.0 MB x bf16
  unsigned short* wqT   = (unsigned short*)(ws +  8388608);   //  6.0 MB Wqkv^T
  unsigned short* woT   = (unsigned short*)(ws + 14680064);   //  2.0 MB Wout^T
  unsigned short* qkvb  = (unsigned short*)(ws + 16777216);   // 24.0 MB qkv
  unsigned short* attnb = (unsigned short*)(ws + 41943040);   //  8.0 MB attn out
  unsigned short* vTb   = (unsigned short*)(ws + 50331648);   //  8.0 MB V^T

  hipFuncSetAttribute((const void*)k_gemm8,
                      hipFuncAttributeMaxDynamicSharedMemorySize, 131072);

  k_f32_to_bf16<<<4096, 256, 0, stream>>>(x, xb, 1048576);
  k_transpose_w<<<dim3(3072 / 32, 1024 / 32), dim3(32, 8), 0, stream>>>(Wqkv, wqT, 1024, 3072);
  k_transpose_w<<<dim3(1024 / 32, 1024 / 32), dim3(32, 8), 0, stream>>>(Wout, woT, 1024, 1024);
  k_gemm8<<<dim3(3072 / 256, 4096 / 256), 512, 131072, stream>>>(xb, wqT, bqkv, qkvb,
                                                                 4096, 3072, 1024);
  k_transpose_v<<<dim3(16, 32, 2), 256, 0, stream>>>(qkvb, vTb);
  k_attn3<<<dim3(2048 / 64, 32), 256, 0, stream>>>(qkvb, vTb, attnb);
  k_gemm<64, true><<<dim3(1024 / 64, 4096 / 128), 256, 0, stream>>>(attnb, woT, bout, out,
                                                                    4096, 1024, 1024);
}

// Round 4
// 104.326 us; speedup vs baseline: 1.1827x; 1.0116x over previous
//
#include <hip/hip_runtime.h>
#include <stdint.h>

// ---------------------------------------------------------------------------
// WindowedAttn: x(2,2048,1024) f32 -> QKV proj -> windowed causal attn (W=256)
// -> out proj. bf16 MFMA pipeline, f32 in/out.
// Round 4: single GEMM template k_gemmr<BN>: 128xBN tile, 4 waves, ring-4
// K-half slots, counted vmcnt (8/4/0), 64KB LDS -> 2 blocks/CU TLP,
// XCD-swizzled grid. QKV: BN=128 grid 768; out-proj: BN=64 grid 512.
// ---------------------------------------------------------------------------

typedef __attribute__((ext_vector_type(8))) short bf16x8;     // 8 bf16 (4 VGPR)
typedef __attribute__((ext_vector_type(4))) float f32x4;      // MFMA C/D
typedef __attribute__((ext_vector_type(4))) unsigned int u32x4;
typedef __attribute__((ext_vector_type(4))) unsigned short u16x4;

#define DEV static __device__ __forceinline__

DEV unsigned short f2bf(float f) {            // f32 -> bf16 RNE
  unsigned int u = __builtin_bit_cast(unsigned int, f);
  u += 0x7fffu + ((u >> 16) & 1u);
  return (unsigned short)(u >> 16);
}

DEV void gload_lds16(const void* g, void* l) { // 16B global -> LDS direct
  __builtin_amdgcn_global_load_lds((const __attribute__((address_space(1))) void*)g,
                                   (__attribute__((address_space(3))) void*)l,
                                   16, 0, 0);
}

// --------------------------- fp32 -> bf16 ----------------------------------
__global__ __launch_bounds__(256) void k_f32_to_bf16(const float* __restrict__ in,
                                                     unsigned short* __restrict__ out,
                                                     int n4) {
  int i = blockIdx.x * 256 + threadIdx.x;
  if (i >= n4) return;
  f32x4 v = ((const f32x4*)in)[i];
  u16x4 o;
  o[0] = f2bf(v[0]); o[1] = f2bf(v[1]); o[2] = f2bf(v[2]); o[3] = f2bf(v[3]);
  ((u16x4*)out)[i] = o;
}

// ------------------- transpose + convert: out[n][k] = in[k][n] -------------
__global__ __launch_bounds__(256) void k_transpose_w(const float* __restrict__ in,
                                                     unsigned short* __restrict__ out,
                                                     int K, int N) {
  __shared__ float t[32][33];
  const int tx = threadIdx.x, ty = threadIdx.y;
  const int n0 = blockIdx.x * 32, k0 = blockIdx.y * 32;
#pragma unroll
  for (int i = 0; i < 4; ++i)
    t[ty + i * 8][tx] = in[(size_t)(k0 + ty + i * 8) * N + n0 + tx];
  __syncthreads();
#pragma unroll
  for (int i = 0; i < 4; ++i)
    out[(size_t)(n0 + ty + i * 8) * K + k0 + tx] = f2bf(t[tx][ty + i * 8]);
}

// ---------------- V transpose: vT[b*1024+hd][s] = qkv[b,s,2048+hd] ---------
__global__ __launch_bounds__(256) void k_transpose_v(const unsigned short* __restrict__ qkv,
                                                     unsigned short* __restrict__ vT) {
  __shared__ unsigned short t[64][80];
  const int tid = threadIdx.x;
  const int hd0 = blockIdx.x * 64;
  const int s0  = blockIdx.y * 64;
  const int b   = blockIdx.z;
  const unsigned short* src = qkv + (size_t)b * 2048 * 3072 + 2048;
#pragma unroll
  for (int rep = 0; rep < 2; ++rep) {
    int idx = rep * 256 + tid;
    int rs = idx >> 3;
    int sl = idx & 7;
    u32x4 v = *(const u32x4*)(src + (size_t)(s0 + rs) * 3072 + hd0 + sl * 8);
#pragma unroll
    for (int j = 0; j < 8; ++j)
      t[sl * 8 + j][rs] = (unsigned short)(v[j >> 1] >> ((j & 1) * 16));
  }
  __syncthreads();
  unsigned short* dst = vT + (size_t)b * 1024 * 2048;
#pragma unroll
  for (int rep = 0; rep < 2; ++rep) {
    int idx = rep * 256 + tid;
    int hd = idx >> 3;
    int sl = idx & 7;
    *(u32x4*)(dst + (size_t)(hd0 + hd) * 2048 + s0 + sl * 8) = *(const u32x4*)&t[hd][sl * 8];
  }
}

// ---------------- ring-4 counted-vmcnt GEMM: C = A @ Bt^T + bias -----------
// 128 x BN tile, 256 threads (4 waves 2x2; wave tile 64 x BN/2). K-half = 32.
// LDS: As[4][128][32] + Bs[4][BN][32] (64KB at BN=128 -> 2 blocks/CU).
// Per phase h: {frag ds_reads(slot h&3); stage(h+3) -> slot (h-1)&3;
//   sched_pin; s_barrier; lgkmcnt(0); setprio MFMA setprio; counted vmcnt;
//   s_barrier}. vmcnt mid-loop = 2 stages in flight (8 or 6 loads), tail
//   4/3 then 0. Latency budget: half consumed 3 phases after issue + 2-block
//   TLP covers the remainder (m114 implicit overlap).
template <int BN, bool F32OUT>
__global__ __launch_bounds__(256, 2) void k_gemmr(const unsigned short* __restrict__ A,
                                                  const unsigned short* __restrict__ Bt,
                                                  const float* __restrict__ bias,
                                                  void* __restrict__ Cout,
                                                  int M, int N, int K) {
  constexpr int NI = BN / 32;               // B frags per wave
  __shared__ unsigned short As[4 * 128 * 32];
  __shared__ unsigned short Bs[4 * BN * 32];
  const int tid = threadIdx.x, lane = tid & 63, wid = tid >> 6;
  const int wr = wid >> 1, wc = wid & 1;
  const int g = lane >> 4, li = lane & 15;

  // XCD-aware swizzle (grid size divisible by 8 in all uses)
  const int gx = gridDim.x;
  const int nwg = gx * gridDim.y;
  const int flat = blockIdx.y * gx + blockIdx.x;
  const int swz = (flat & 7) * (nwg >> 3) + (flat >> 3);
  const int m0 = (swz / gx) * 128, n0 = (swz % gx) * BN;

  const int NH = K >> 5;                    // K-halves
  const int kp = g ^ ((li >> 1) & 3);       // physical k-slot for frag reads
  const int skl = (lane & 3) ^ ((lane >> 3) & 3);  // logical slot for staging
  constexpr int BSLOT = BN * 32;

  f32x4 acc[4][NI] = {};

  auto stage = [&](int h) {
    const int slot = h & 3;
    const int rin = lane >> 2;
#pragma unroll
    for (int j = 0; j < 2; ++j) {
      int c = wid * 2 + j;                  // 8 A-chunks of 16 rows
      gload_lds16(A + (size_t)(m0 + c * 16 + rin) * K + h * 32 + skl * 8,
                  &As[slot * 4096 + c * 512]);
    }
    if (BN == 128) {
#pragma unroll
      for (int j = 0; j < 2; ++j) {
        int c = wid * 2 + j;
        gload_lds16(Bt + (size_t)(n0 + c * 16 + rin) * K + h * 32 + skl * 8,
                    &Bs[slot * BSLOT + c * 512]);
      }
    } else {
      int c = wid;                          // 4 B-chunks
      gload_lds16(Bt + (size_t)(n0 + c * 16 + rin) * K + h * 32 + skl * 8,
                  &Bs[slot * BSLOT + c * 512]);
    }
  };

  // prologue: stage halves 0..2, wait for half 0 (2 stages may stay in flight)
  stage(0); stage(1); stage(2);
  if (BN == 128) asm volatile("s_waitcnt vmcnt(8)" ::: "memory");
  else           asm volatile("s_waitcnt vmcnt(6)" ::: "memory");
  __builtin_amdgcn_s_barrier();

  for (int h = 0; h < NH; ++h) {
    const int slot = h & 3;
    bf16x8 af[4], bfv[NI];
#pragma unroll
    for (int mi = 0; mi < 4; ++mi)
      af[mi] = *(const bf16x8*)&As[slot * 4096 + (wr * 64 + mi * 16 + li) * 32 + kp * 8];
#pragma unroll
    for (int nj = 0; nj < NI; ++nj)
      bfv[nj] = *(const bf16x8*)&Bs[slot * BSLOT + (wc * (BN / 2) + nj * 16 + li) * 32 + kp * 8];
    if (h + 3 < NH) stage(h + 3);
    __builtin_amdgcn_sched_barrier(0);      // pin ds_reads + gloads before barrier
    __builtin_amdgcn_s_barrier();
    asm volatile("s_waitcnt lgkmcnt(0)" ::: "memory");
    __builtin_amdgcn_sched_barrier(0);      // rule 18: MFMA must not hoist above
    __builtin_amdgcn_s_setprio(1);
#pragma unroll
    for (int mi = 0; mi < 4; ++mi)
#pragma unroll
      for (int nj = 0; nj < NI; ++nj)
        acc[mi][nj] = __builtin_amdgcn_mfma_f32_16x16x32_bf16(af[mi], bfv[nj],
                                                              acc[mi][nj], 0, 0, 0);
    __builtin_amdgcn_s_setprio(0);
    // tail-aware counted vmcnt: guarantee half h+1 landed; never 0 mid-loop
    if (BN == 128) {
      if (h + 3 < NH)       asm volatile("s_waitcnt vmcnt(8)" ::: "memory");
      else if (h + 3 == NH) asm volatile("s_waitcnt vmcnt(4)" ::: "memory");
      else if (h + 2 == NH) asm volatile("s_waitcnt vmcnt(0)" ::: "memory");
    } else {
      if (h + 3 < NH)       asm volatile("s_waitcnt vmcnt(6)" ::: "memory");
      else if (h + 3 == NH) asm volatile("s_waitcnt vmcnt(3)" ::: "memory");
      else if (h + 2 == NH) asm volatile("s_waitcnt vmcnt(0)" ::: "memory");
    }
    __builtin_amdgcn_sched_barrier(0);
    if (h + 1 < NH) __builtin_amdgcn_s_barrier();
  }

  // epilogue: C/D layout col = li, row = g*4 + reg
  float bv[NI];
#pragma unroll
  for (int nj = 0; nj < NI; ++nj) bv[nj] = bias[n0 + wc * (BN / 2) + nj * 16 + li];
#pragma unroll
  for (int mi = 0; mi < 4; ++mi) {
#pragma unroll
    for (int nj = 0; nj < NI; ++nj) {
      const int col = n0 + wc * (BN / 2) + nj * 16 + li;
#pragma unroll
      for (int reg = 0; reg < 4; ++reg) {
        const int row = m0 + wr * 64 + mi * 16 + g * 4 + reg;
        float v = acc[mi][nj][reg] + bv[nj];
        if (F32OUT) ((float*)Cout)[(size_t)row * N + col] = v;
        else ((unsigned short*)Cout)[(size_t)row * N + col] = f2bf(v);
      }
    }
  }
}

// ------------------ windowed flash attention (staged, dbuf) ----------------
// qkv: (4096,3072) bf16 = [Q|K|V]; vT: per (b,h) 64 d-rows x 2048 keys.
// Block = (b,h,q-tile 64), 4 waves x 16 q-rows. K and V^T staged via
// global_load_lds (linear dest, XOR slot pre-swizzle both sides),
// double-buffered with counted vmcnt(4).
__global__ __launch_bounds__(256) void k_attn3(const unsigned short* __restrict__ qkv,
                                               const unsigned short* __restrict__ vT,
                                               unsigned short* __restrict__ attn) {
  __shared__ unsigned short Ks[2][64 * 64];
  __shared__ unsigned short Vs[2][64 * 64];
  __shared__ unsigned short Ps[64 * 88];
  const int tid = threadIdx.x, lane = tid & 63, wid = tid >> 6;
  const int g = lane >> 4, li = lane & 15;
  const int bh = blockIdx.y, b = bh >> 4, h = bh & 15;
  const int q0 = blockIdx.x * 64;
  const size_t rs = 3072;
  const unsigned short* qb = qkv + (size_t)b * 2048 * rs + h * 64;
  const unsigned short* kb = qb + 1024;
  const unsigned short* vb = vT + (size_t)bh * 64 * 2048;

  const int qrow = wid * 16 + li;
  const bf16x8 qf0 = *(const bf16x8*)(qb + (size_t)(q0 + qrow) * rs + (g << 3));
  const bf16x8 qf1 = *(const bf16x8*)(qb + (size_t)(q0 + qrow) * rs + 32 + (g << 3));

  const int tf = (blockIdx.x >= 4) ? 0 : (4 - (int)blockIdx.x);

  auto stage = [&](int bufi, int t) {
    const int j0 = q0 - 256 + t * 64;
    const int sl = (lane & 7) ^ ((lane >> 3) & 7);
#pragma unroll
    for (int j = 0; j < 2; ++j) {
      const int chunk = wid * 2 + j;
      const int row = chunk * 8 + (lane >> 3);
      gload_lds16(kb + (size_t)(j0 + row) * rs + sl * 8, &Ks[bufi][chunk * 512]);
      gload_lds16(vb + (size_t)row * 2048 + j0 + sl * 8, &Vs[bufi][chunk * 512]);
    }
  };

  f32x4 o[4] = {};
  float m_run[4] = {-3e30f, -3e30f, -3e30f, -3e30f};
  float l_part[4] = {0.f, 0.f, 0.f, 0.f};

  stage(0, tf);
  int cur = 0;
  for (int t = tf; t < 5; ++t) {
    if (t + 1 < 5) {
      stage(cur ^ 1, t + 1);
      asm volatile("s_waitcnt vmcnt(4)" ::: "memory");
    } else {
      asm volatile("s_waitcnt vmcnt(0)" ::: "memory");
    }
    __builtin_amdgcn_sched_barrier(0);
    __builtin_amdgcn_s_barrier();
    __builtin_amdgcn_sched_barrier(0);

    const unsigned short* Kc = Ks[cur];
    const unsigned short* Vc = Vs[cur];

    f32x4 s[4];
#pragma unroll
    for (int ni = 0; ni < 4; ++ni) {
      const int kr = ni * 16 + li;
      const int sw = (kr & 7);
      bf16x8 kf0 = *(const bf16x8*)&Kc[kr * 64 + ((g ^ sw) << 3)];
      bf16x8 kf1 = *(const bf16x8*)&Kc[kr * 64 + (((4 + g) ^ sw) << 3)];
      f32x4 z = {};
      z = __builtin_amdgcn_mfma_f32_16x16x32_bf16(qf0, kf0, z, 0, 0, 0);
      z = __builtin_amdgcn_mfma_f32_16x16x32_bf16(qf1, kf1, z, 0, 0, 0);
      s[ni] = z;
    }
    const int rt = wid * 16 + g * 4;
#pragma unroll
    for (int ni = 0; ni < 4; ++ni) {
      int ct = ni * 16 + li;
#pragma unroll
      for (int reg = 0; reg < 4; ++reg) {
        float sv = s[ni][reg] * 0.125f;
        if (t == 4 && ct > rt + reg) sv = -3e30f;   // causal
        if (t == 0 && ct < rt + reg) sv = -3e30f;   // window lower bound
        s[ni][reg] = sv;
      }
    }
    float alpha[4];
#pragma unroll
    for (int reg = 0; reg < 4; ++reg) {
      float mx = fmaxf(fmaxf(s[0][reg], s[1][reg]), fmaxf(s[2][reg], s[3][reg]));
      mx = fmaxf(mx, __shfl_xor(mx, 1, 64));
      mx = fmaxf(mx, __shfl_xor(mx, 2, 64));
      mx = fmaxf(mx, __shfl_xor(mx, 4, 64));
      mx = fmaxf(mx, __shfl_xor(mx, 8, 64));
      float mnew = fmaxf(m_run[reg], mx);
      alpha[reg] = __expf(m_run[reg] - mnew);
      m_run[reg] = mnew;
    }
#pragma unroll
    for (int reg = 0; reg < 4; ++reg) {
      float ps = 0.f;
#pragma unroll
      for (int ni = 0; ni < 4; ++ni) {
        float p = __expf(s[ni][reg] - m_run[reg]);
        ps += p;
        Ps[(wid * 16 + g * 4 + reg) * 88 + ni * 16 + li] = f2bf(p);
      }
      l_part[reg] = l_part[reg] * alpha[reg] + ps;
#pragma unroll
      for (int ni = 0; ni < 4; ++ni) o[ni][reg] *= alpha[reg];
    }
    asm volatile("s_waitcnt lgkmcnt(0)" ::: "memory");
    __builtin_amdgcn_sched_barrier(0);
    const bf16x8 pf0 = *(const bf16x8*)&Ps[(wid * 16 + li) * 88 + (g << 3)];
    const bf16x8 pf1 = *(const bf16x8*)&Ps[(wid * 16 + li) * 88 + 32 + (g << 3)];
#pragma unroll
    for (int ni = 0; ni < 4; ++ni) {
      const int dr = ni * 16 + li;
      const int sw = (dr & 7);
      bf16x8 vf0 = *(const bf16x8*)&Vc[dr * 64 + ((g ^ sw) << 3)];
      bf16x8 vf1 = *(const bf16x8*)&Vc[dr * 64 + (((4 + g) ^ sw) << 3)];
      o[ni] = __builtin_amdgcn_mfma_f32_16x16x32_bf16(pf0, vf0, o[ni], 0, 0, 0);
      o[ni] = __builtin_amdgcn_mfma_f32_16x16x32_bf16(pf1, vf1, o[ni], 0, 0, 0);
    }
    __builtin_amdgcn_sched_barrier(0);
    __builtin_amdgcn_s_barrier();
    cur ^= 1;
  }

  float inv[4];
#pragma unroll
  for (int reg = 0; reg < 4; ++reg) {
    float L = l_part[reg];
    L += __shfl_xor(L, 1, 64);
    L += __shfl_xor(L, 2, 64);
    L += __shfl_xor(L, 4, 64);
    L += __shfl_xor(L, 8, 64);
    inv[reg] = 1.f / L;
  }
#pragma unroll
  for (int ni = 0; ni < 4; ++ni) {
#pragma unroll
    for (int reg = 0; reg < 4; ++reg) {
      size_t row = (size_t)b * 2048 + q0 + wid * 16 + g * 4 + reg;
      attn[row * 1024 + h * 64 + ni * 16 + li] = f2bf(o[ni][reg] * inv[reg]);
    }
  }
}

// ---------------------------------------------------------------------------
extern "C" void kernel_launch(void* const* d_in, const int* in_sizes, int n_in,
                              void* d_out, int out_size, void* d_ws, size_t ws_size,
                              hipStream_t stream) {
  const float* x    = (const float*)d_in[0];   // (4096, 1024)
  const float* Wqkv = (const float*)d_in[1];   // (1024, 3072)
  const float* bqkv = (const float*)d_in[2];   // (3072)
  const float* Wout = (const float*)d_in[3];   // (1024, 1024)
  const float* bout = (const float*)d_in[4];   // (1024)
  float* out = (float*)d_out;                  // (4096, 1024)

  uint8_t* ws = (uint8_t*)d_ws;
  unsigned short* xb    = (unsigned short*)(ws);              //  8.0 MB x bf16
  unsigned short* wqT   = (unsigned short*)(ws +  8388608);   //  6.0 MB Wqkv^T
  unsigned short* woT   = (unsigned short*)(ws + 14680064);   //  2.0 MB Wout^T
  unsigned short* qkvb  = (unsigned short*)(ws + 16777216);   // 24.0 MB qkv
  unsigned short* attnb = (unsigned short*)(ws + 41943040);   //  8.0 MB attn out
  unsigned short* vTb   = (unsigned short*)(ws + 50331648);   //  8.0 MB V^T

  k_f32_to_bf16<<<4096, 256, 0, stream>>>(x, xb, 1048576);
  k_transpose_w<<<dim3(3072 / 32, 1024 / 32), dim3(32, 8), 0, stream>>>(Wqkv, wqT, 1024, 3072);
  k_transpose_w<<<dim3(1024 / 32, 1024 / 32), dim3(32, 8), 0, stream>>>(Wout, woT, 1024, 1024);
  k_gemmr<128, false><<<dim3(3072 / 128, 4096 / 128), 256, 0, stream>>>(xb, wqT, bqkv, qkvb,
                                                                        4096, 3072, 1024);
  k_transpose_v<<<dim3(16, 32, 2), 256, 0, stream>>>(qkvb, vTb);
  k_attn3<<<dim3(2048 / 64, 32), 256, 0, stream>>>(qkvb, vTb, attnb);
  k_gemmr<64, true><<<dim3(1024 / 64, 4096 / 128), 256, 0, stream>>>(attnb, woT, bout, out,
                                                                     4096, 1024, 1024);
}